// Round 14
// baseline (323.441 us; speedup 1.0000x reference)
//
#include <hip/hip_runtime.h>

#define D_DIM 1024
#define F_DIM 4096
#define E_NUM 16
#define T_NUM 2048

typedef __bf16 bf16x8 __attribute__((ext_vector_type(8)));
typedef float f32x4 __attribute__((ext_vector_type(4)));

__device__ __forceinline__ unsigned pack2bf(float a, float b) {
  unsigned ua = __builtin_bit_cast(unsigned, a);
  unsigned ub = __builtin_bit_cast(unsigned, b);
  return ((ub + 0x8000u) & 0xffff0000u) | ((ua + 0x8000u) >> 16);
}
__device__ __forceinline__ unsigned short f2bf(float a) {
  unsigned ua = __builtin_bit_cast(unsigned, a);
  return (unsigned short)((ua + 0x8000u) >> 16);
}
__device__ __forceinline__ bf16x8 cvt8(f32x4 a, f32x4 b) {
  bf16x8 r;
  r[0] = (__bf16)a[0]; r[1] = (__bf16)a[1]; r[2] = (__bf16)a[2]; r[3] = (__bf16)a[3];
  r[4] = (__bf16)b[0]; r[5] = (__bf16)b[1]; r[6] = (__bf16)b[2]; r[7] = (__bf16)b[3];
  return r;
}
__device__ __forceinline__ void gload16(const void* g, void* l) {
  __builtin_amdgcn_global_load_lds(
      (const __attribute__((address_space(1))) unsigned*)g,
      (__attribute__((address_space(3))) unsigned*)l, 16, 0, 0);
}

// ---------------- router
__global__ __launch_bounds__(256) void moe_router(
    const float* __restrict__ x, const float* __restrict__ gate,
    float* __restrict__ logits_out, int* __restrict__ topi, float* __restrict__ topw)
{
  __shared__ float lg[16][17];
  int tid = threadIdx.x;
  int tbase = blockIdx.x * 16;
  int tt = tid >> 4, e = tid & 15;
  const float4* xr = (const float4*)(x + (size_t)(tbase + tt) * D_DIM);
  const float4* gw = (const float4*)(gate + (size_t)e * D_DIM);
  float acc = 0.f;
  #pragma unroll 4
  for (int k = 0; k < D_DIM / 4; ++k) {
    float4 a = xr[k], b = gw[k];
    acc += a.x * b.x + a.y * b.y + a.z * b.z + a.w * b.w;
  }
  lg[tt][e] = acc;
  logits_out[(size_t)(tbase + tt) * E_NUM + e] = acc;
  __syncthreads();
  if (tid < 16) {
    int t = tid;
    float best = -1e30f; int i0 = 0;
    #pragma unroll
    for (int j = 0; j < 16; ++j) { float v = lg[t][j]; if (v > best) { best = v; i0 = j; } }
    float best1 = -1e30f; int i1 = 0;
    #pragma unroll
    for (int j = 0; j < 16; ++j) { if (j == i0) continue; float v = lg[t][j]; if (v > best1) { best1 = v; i1 = j; } }
    float e1 = __expf(best1 - best);
    float inv = 1.f / (1.f + e1);
    int gt = tbase + t;
    topi[gt * 2]     = i0;  topi[gt * 2 + 1] = i1;
    topw[gt * 2]     = inv; topw[gt * 2 + 1] = e1 * inv;
  }
}

// ---------------- deterministic routing
__global__ __launch_bounds__(1024) void moe_route_build(
    const int* __restrict__ topi,
    int* __restrict__ cnt, int* __restrict__ rowbase,
    int* __restrict__ rowlist, int* __restrict__ rowpos)
{
  __shared__ int scnt[16];
  __shared__ int sbase[17];
  int wave = threadIdx.x >> 6;
  int lane = threadIdx.x & 63;
  int total = 0;
  for (int c = 0; c < (T_NUM * 2) / 64; ++c) {
    int s = c * 64 + lane;
    unsigned long long m = __ballot(topi[s] == wave);
    total += __popcll(m);
  }
  if (lane == 0) scnt[wave] = total;
  __syncthreads();
  if (threadIdx.x == 0) {
    int acc = 0;
    for (int e2 = 0; e2 < 16; ++e2) { sbase[e2] = acc; cnt[e2] = scnt[e2]; acc += scnt[e2]; }
    sbase[16] = acc;
    for (int e2 = 0; e2 <= 16; ++e2) rowbase[e2] = sbase[e2];
  }
  __syncthreads();
  int running = sbase[wave];
  for (int c = 0; c < (T_NUM * 2) / 64; ++c) {
    int s = c * 64 + lane;
    int ei = topi[s];
    unsigned long long m = __ballot(ei == wave);
    if (ei == wave) {
      int pos = running + __popcll(m & ((1ull << lane) - 1ull));
      rowlist[pos] = s;
      rowpos[s] = pos;
    }
    running += __popcll(m);
  }
}

// ---------------- X gather: xg[pos] = bf16(x[rowlist[pos]>>1]) -- compacted, contiguous rows
__global__ __launch_bounds__(256) void moe_gather(
    const float* __restrict__ x, const int* __restrict__ rowlist,
    const int* __restrict__ rowbase, unsigned short* __restrict__ xg)
{
  int pos = blockIdx.x;
  int total = rowbase[16];
  int tok = (pos < total) ? (rowlist[pos] >> 1) : 0;
  f32x4 v = ((const f32x4*)(x + (size_t)tok * D_DIM))[threadIdx.x];
  ((uint2*)(xg + (size_t)pos * D_DIM))[threadIdx.x] =
      make_uint2(pack2bf(v[0], v[1]), pack2bf(v[2], v[3]));
}

// ---------------- GEMM1: H = silu(x@w1^T) * (x@w3^T)
// BM=320 BN=128 BK=32, 512 thr, 1 block/CU. X from CONTIGUOUS xg (compacted).
// UNPINNED grid dim3(32,2,16) (R12 best): expert cohorts are temporally contiguous,
// X re-reads L2/L3-served. W staged exactly once. 2-deep counted-vmcnt pipeline {7,6}.
// LDS: X 2x20K @0 | W1 2x16K @40960 | W3 2x16K @73728 = 104 KB.
__global__ __launch_bounds__(512, 2) void moe_gemm1(
    const unsigned short* __restrict__ xg, const float* __restrict__ w1s, const float* __restrict__ w3s,
    const int* __restrict__ cnt, const int* __restrict__ rowbase,
    unsigned short* __restrict__ H)
{
  int nt = blockIdx.x, mt = blockIdx.y, e = blockIdx.z;
  int Ne = cnt[e];
  if (mt * 320 >= Ne) return;
  int rbase = rowbase[e];

  __shared__ char smem[106496];

  int tid = threadIdx.x, lane = tid & 63, wave = tid >> 6;

  // X staging: 20 chunks of 1KB (16 contiguous xg rows x 64B); wave w: {w, w+8, w+16 if w<4}
  // source swizzle: LDS slot s holds global k-chunk s^((row>>1)&3)
  const char* px[3];
  unsigned xoff[3];
  #pragma unroll
  for (int it = 0; it < 3; ++it) {
    int ch = wave + it * 8;
    if (ch < 20) {
      int row = ch * 16 + (lane >> 2);
      int slot = (lane & 3) ^ ((row >> 1) & 3);
      px[it] = (const char*)(xg + (size_t)(rbase + mt * 320 + row) * D_DIM) + slot * 16;
      xoff[it] = (unsigned)(ch * 1024 + lane * 16);
    } else {
      px[it] = (const char*)xg;
      xoff[it] = 0;
    }
  }

  // W staging: 16 chunks (8 rows x 128B); wave owns 2w, 2w+1
  const float* w1e = w1s + (size_t)e * F_DIM * D_DIM + (size_t)(nt * 128) * D_DIM;
  const float* w3e = w3s + (size_t)e * F_DIM * D_DIM + (size_t)(nt * 128) * D_DIM;
  const char* p1[2]; const char* p3[2];
  #pragma unroll
  for (int it = 0; it < 2; ++it) {
    int r = (wave * 2 + it) * 8 + (lane >> 3);
    int c = (lane & 7) ^ (r & 7);
    p1[it] = (const char*)(w1e + (size_t)r * D_DIM) + c * 16;
    p3[it] = (const char*)(w3e + (size_t)r * D_DIM) + c * 16;
  }

  // wave map: 4M x 2N, wave-tile 80x64
  int wm = wave >> 1, wn = wave & 1;
  int lr16 = lane & 15, lq = lane >> 4;

  unsigned offA[5];
  #pragma unroll
  for (int mi = 0; mi < 5; ++mi) {
    int m = wm * 80 + mi * 16 + lr16;
    offA[mi] = (unsigned)(m * 64 + ((lq ^ ((m >> 1) & 3)) * 16));
  }
  unsigned offB[4][2];
  #pragma unroll
  for (int ni = 0; ni < 4; ++ni) {
    int n = wn * 64 + ni * 16 + lr16;
    #pragma unroll
    for (int h = 0; h < 2; ++h)
      offB[ni][h] = (unsigned)(n * 128 + (((lq * 2 + h) ^ (n & 7)) * 16));
  }

  unsigned wdst = (unsigned)((wave * 2) * 1024 + lane * 16);

  f32x4 acc1[5][4], acc3[5][4];
  #pragma unroll
  for (int i = 0; i < 5; ++i)
    #pragma unroll
    for (int j = 0; j < 4; ++j) { acc1[i][j] = {0.f,0.f,0.f,0.f}; acc3[i][j] = {0.f,0.f,0.f,0.f}; }

  auto STAGE = [&](unsigned bsel, int ks) {
    gload16(px[0] + ks * 64, smem + bsel * 20480u + xoff[0]);
    gload16(px[1] + ks * 64, smem + bsel * 20480u + xoff[1]);
    if (wave < 4) gload16(px[2] + ks * 64, smem + bsel * 20480u + xoff[2]);
    #pragma unroll
    for (int it = 0; it < 2; ++it) {
      gload16(p1[it] + ks * 128, smem + 40960 + bsel * 16384u + wdst + it * 1024);
      gload16(p3[it] + ks * 128, smem + 73728 + bsel * 16384u + wdst + it * 1024);
    }
  };

  STAGE(0, 0);
  unsigned buf = 0;
  for (int ks = 0; ks < 32; ++ks) {
    if (ks < 31) {
      STAGE(buf ^ 1u, ks + 1);
      if (wave < 4) asm volatile("s_waitcnt vmcnt(7)" ::: "memory");
      else          asm volatile("s_waitcnt vmcnt(6)" ::: "memory");
    } else {
      asm volatile("s_waitcnt vmcnt(0)" ::: "memory");
    }
    __builtin_amdgcn_s_barrier();
    unsigned xb = buf * 20480u;
    unsigned w1b = 40960 + buf * 16384u;
    unsigned w3b = 73728 + buf * 16384u;
    bf16x8 af[5];
    #pragma unroll
    for (int mi = 0; mi < 5; ++mi)
      af[mi] = *(const bf16x8*)(smem + xb + offA[mi]);
    #pragma unroll
    for (int ni = 0; ni < 4; ++ni) {
      bf16x8 b1 = cvt8(*(const f32x4*)(smem + w1b + offB[ni][0]),
                       *(const f32x4*)(smem + w1b + offB[ni][1]));
      bf16x8 b3 = cvt8(*(const f32x4*)(smem + w3b + offB[ni][0]),
                       *(const f32x4*)(smem + w3b + offB[ni][1]));
      #pragma unroll
      for (int mi = 0; mi < 5; ++mi) {
        acc1[mi][ni] = __builtin_amdgcn_mfma_f32_16x16x32_bf16(af[mi], b1, acc1[mi][ni], 0, 0, 0);
        acc3[mi][ni] = __builtin_amdgcn_mfma_f32_16x16x32_bf16(af[mi], b3, acc3[mi][ni], 0, 0, 0);
      }
    }
    __builtin_amdgcn_s_barrier();
    buf ^= 1u;
  }

  #pragma unroll
  for (int mi = 0; mi < 5; ++mi) {
    int mb = wm * 80 + mi * 16 + lq * 4;
    #pragma unroll
    for (int r = 0; r < 4; ++r) {
      int lrow = mt * 320 + mb + r;
      if (lrow < Ne) {
        size_t hrow = (size_t)(rbase + lrow) * F_DIM;
        #pragma unroll
        for (int ni = 0; ni < 4; ++ni) {
          int f = nt * 128 + wn * 64 + ni * 16 + lr16;
          float a1v = acc1[mi][ni][r];
          float a3v = acc3[mi][ni][r];
          float hv = (a1v / (1.f + __expf(-a1v))) * a3v;
          H[hrow + f] = f2bf(hv);
        }
      }
    }
  }
}

// ---------------- GEMM2: Y = H @ w2^T (bf16 out)
// BM=320 BN=128 BK=64, 512 thr, 1 block/CU.
// XCD-PINNED 1D grid (256) -- R13 best: H slice (2.1MB/expert) L2-resident per XCD.
// Uniform 9 loads/wave, vmcnt(9). LDS: A 2x40K @0 | B 2x32K @81920 = 144 KB.
__global__ __launch_bounds__(512, 2) void moe_gemm2(
    const unsigned short* __restrict__ H, const float* __restrict__ w2s,
    const int* __restrict__ cnt, const int* __restrict__ rowbase,
    unsigned short* __restrict__ Ybf)
{
  int bid = blockIdx.x;
  int xcd = bid & 7, sub = bid >> 3;
  int e  = xcd * 2 + (sub >> 4);
  int nt = sub & 7;
  int mt = (sub >> 3) & 1;
  int Ne = cnt[e];
  if (mt * 320 >= Ne) return;
  int rbase = rowbase[e];

  __shared__ char smem[147456];

  int tid = threadIdx.x, lane = tid & 63, wave = tid >> 6;

  // A staging: 40 chunks (8 rows x 128B); wave w: {w, w+8, w+16, w+24, w+32}
  const char* pa[5];
  unsigned aoff[5];
  #pragma unroll
  for (int it = 0; it < 5; ++it) {
    int ch = wave + it * 8;
    int row = ch * 8 + (lane >> 3);
    int grow = mt * 320 + row; if (grow >= Ne) grow = Ne - 1;
    int c8 = (lane & 7) ^ (row & 7);
    pa[it] = (const char*)(H + (size_t)(rbase + grow) * F_DIM) + c8 * 16;
    aoff[it] = (unsigned)(ch * 1024 + lane * 16);
  }

  // B staging: 32 chunks (4 rows x 256B); wave w: {w, w+8, w+16, w+24}
  const float* w2e = w2s + (size_t)e * D_DIM * F_DIM + (size_t)(nt * 128) * F_DIM;
  const char* pb[4];
  unsigned boff[4];
  #pragma unroll
  for (int it = 0; it < 4; ++it) {
    int ch = wave + it * 8;
    int row = ch * 4 + (lane >> 4);
    int c = (lane & 15) ^ (row & 7);
    pb[it] = (const char*)(w2e + (size_t)row * F_DIM) + c * 16;
    boff[it] = (unsigned)(ch * 1024 + lane * 16);
  }

  // wave map: 4M x 2N, wave-tile 80x64
  int wm = wave >> 1, wn = wave & 1;
  int lr16 = lane & 15, lq = lane >> 4;

  f32x4 acc[5][4];
  #pragma unroll
  for (int i = 0; i < 5; ++i)
    #pragma unroll
    for (int j = 0; j < 4; ++j) acc[i][j] = {0.f, 0.f, 0.f, 0.f};

  auto STAGE = [&](unsigned bsel, int ks) {
    #pragma unroll
    for (int it = 0; it < 5; ++it)
      gload16(pa[it] + ks * 128, smem + bsel * 40960u + aoff[it]);
    #pragma unroll
    for (int it = 0; it < 4; ++it)
      gload16(pb[it] + ks * 256, smem + 81920 + bsel * 32768u + boff[it]);
  };

  STAGE(0, 0);
  unsigned buf = 0;
  for (int ks = 0; ks < 64; ++ks) {
    if (ks < 63) {
      STAGE(buf ^ 1u, ks + 1);
      asm volatile("s_waitcnt vmcnt(9)" ::: "memory");
    } else {
      asm volatile("s_waitcnt vmcnt(0)" ::: "memory");
    }
    __builtin_amdgcn_s_barrier();
    unsigned ab = buf * 40960u;
    unsigned bb = 81920 + buf * 32768u;
    #pragma unroll
    for (int ksub = 0; ksub < 2; ++ksub) {
      bf16x8 bfr[4];
      #pragma unroll
      for (int ni = 0; ni < 4; ++ni) {
        int n = wn * 64 + ni * 16 + lr16;
        unsigned o0 = (unsigned)(n * 256 + (((ksub * 8 + lq * 2 + 0) ^ (n & 7)) * 16));
        unsigned o1 = (unsigned)(n * 256 + (((ksub * 8 + lq * 2 + 1) ^ (n & 7)) * 16));
        bfr[ni] = cvt8(*(const f32x4*)(smem + bb + o0), *(const f32x4*)(smem + bb + o1));
      }
      #pragma unroll
      for (int mi = 0; mi < 5; ++mi) {
        int m = wm * 80 + mi * 16 + lr16;
        unsigned off = (unsigned)(m * 128 + (((ksub * 4 + lq) ^ (m & 7)) * 16));
        bf16x8 af = *(const bf16x8*)(smem + ab + off);
        #pragma unroll
        for (int ni = 0; ni < 4; ++ni)
          acc[mi][ni] = __builtin_amdgcn_mfma_f32_16x16x32_bf16(af, bfr[ni], acc[mi][ni], 0, 0, 0);
      }
    }
    __builtin_amdgcn_s_barrier();
    buf ^= 1u;
  }

  #pragma unroll
  for (int mi = 0; mi < 5; ++mi) {
    int mb = wm * 80 + mi * 16 + lq * 4;
    #pragma unroll
    for (int r = 0; r < 4; ++r) {
      int lrow = mt * 320 + mb + r;
      if (lrow < Ne) {
        size_t yrow = (size_t)(rbase + lrow) * D_DIM;
        #pragma unroll
        for (int ni = 0; ni < 4; ++ni) {
          int d = nt * 128 + wn * 64 + ni * 16 + lr16;
          Ybf[yrow + d] = f2bf(acc[mi][ni][r]);
        }
      }
    }
  }
}

// ---------------- combine
__global__ __launch_bounds__(128) void moe_combine(
    const unsigned short* __restrict__ Ybf, const int* __restrict__ rowpos,
    const float* __restrict__ topw, float* __restrict__ out)
{
  int t = blockIdx.x, tid = threadIdx.x;
  int r0 = rowpos[t * 2], r1 = rowpos[t * 2 + 1];
  float p0 = topw[t * 2], p1 = topw[t * 2 + 1];
  uint4 a = ((const uint4*)(Ybf + (size_t)r0 * D_DIM))[tid];
  uint4 b = ((const uint4*)(Ybf + (size_t)r1 * D_DIM))[tid];
  float4 o0, o1;
  #define LO(u) __builtin_bit_cast(float, (unsigned)((u) << 16))
  #define HI(u) __builtin_bit_cast(float, (unsigned)((u) & 0xffff0000u))
  o0.x = p0 * LO(a.x) + p1 * LO(b.x);  o0.y = p0 * HI(a.x) + p1 * HI(b.x);
  o0.z = p0 * LO(a.y) + p1 * LO(b.y);  o0.w = p0 * HI(a.y) + p1 * HI(b.y);
  o1.x = p0 * LO(a.z) + p1 * LO(b.z);  o1.y = p0 * HI(a.z) + p1 * HI(b.z);
  o1.z = p0 * LO(a.w) + p1 * LO(b.w);  o1.w = p0 * HI(a.w) + p1 * HI(b.w);
  #undef LO
  #undef HI
  float4* orow = (float4*)(out + (size_t)t * D_DIM);
  orow[tid * 2]     = o0;
  orow[tid * 2 + 1] = o1;
}

extern "C" void kernel_launch(void* const* d_in, const int* in_sizes, int n_in,
                              void* d_out, int out_size, void* d_ws, size_t ws_size,
                              hipStream_t stream) {
  const float* x    = (const float*)d_in[0];
  const float* gate = (const float*)d_in[1];
  const float* w1   = (const float*)d_in[2];
  const float* w2   = (const float*)d_in[3];
  const float* w3   = (const float*)d_in[4];
  float* out    = (float*)d_out;
  float* logits = out + (size_t)T_NUM * D_DIM;

  char* ws = (char*)d_ws;
  int*   cnt     = (int*)(ws + 0);
  int*   rowbase = (int*)(ws + 64);
  int*   topi    = (int*)(ws + 1024);
  float* topw    = (float*)(ws + 1024 + 16384);
  int*   rowlist = (int*)(ws + 1024 + 32768);
  int*   rowpos  = (int*)(ws + 1024 + 49152);
  unsigned short* H  = (unsigned short*)(ws + 131072);                 // 32 MB
  // xg (6144 rows, 12.6 MB) and Ybf (4096 rows, 8 MB) share one region:
  // xg is dead before gemm2 writes Ybf.
  unsigned short* xg  = (unsigned short*)(ws + 131072 + 33554432);
  unsigned short* Ybf = xg;

  moe_router<<<T_NUM / 16, 256, 0, stream>>>(x, gate, logits, topi, topw);
  moe_route_build<<<1, 1024, 0, stream>>>(topi, cnt, rowbase, rowlist, rowpos);
  moe_gather<<<6144, 256, 0, stream>>>(x, rowlist, rowbase, xg);
  moe_gemm1<<<dim3(32, 2, 16), 512, 0, stream>>>(xg, w1, w3, cnt, rowbase, H);
  moe_gemm2<<<256, 512, 0, stream>>>(H, w2, cnt, rowbase, Ybf);
  moe_combine<<<T_NUM, 128, 0, stream>>>(Ybf, rowpos, topw, out);
}